// Round 8
// baseline (498.565 us; speedup 1.0000x reference)
//
#include <hip/hip_runtime.h>

#define FD 96
#define NB12 12     // 16B (8-elem bf16) chunks per row
#define BSH 7       // 128 nodes per bucket
#define BNODES 128

typedef float  f32x4 __attribute__((ext_vector_type(4)));
typedef short  s16x8 __attribute__((ext_vector_type(8)));

__device__ __forceinline__ unsigned short f2bf(float x) {
    unsigned u = __float_as_uint(x);
    u = (u + 0x7fffu + ((u >> 16) & 1u)) >> 16;
    return (unsigned short)u;
}
__device__ __forceinline__ float bflo(unsigned u) { return __uint_as_float(u << 16); }
__device__ __forceinline__ float bfhi(unsigned u) { return __uint_as_float(u & 0xffff0000u); }

// ---------------- bucketed CSR build ----------------

// 1) bucket histogram (LDS-aggregated)
__global__ void k_bcount(const int* __restrict__ dst, int* __restrict__ bcnt, int E, int nbkt) {
    __shared__ int hist[512];
    int tid = threadIdx.x;
    if (tid < 512) hist[tid] = 0;
    __syncthreads();
    for (int i = blockIdx.x * blockDim.x + tid; i < E; i += gridDim.x * blockDim.x)
        atomicAdd(&hist[dst[i] >> BSH], 1);
    __syncthreads();
    if (tid < nbkt && hist[tid]) atomicAdd(&bcnt[tid], hist[tid]);
}

// 2) exclusive scan over bucket counts (1 block, 512 threads)
__global__ void k_bscan(const int* __restrict__ bcnt, int* __restrict__ bbase,
                        int* __restrict__ bcursor, int nbkt) {
    __shared__ int sh[512];
    int tid = threadIdx.x;
    int v = (tid < nbkt) ? bcnt[tid] : 0;
    sh[tid] = v;
    __syncthreads();
    for (int off = 1; off < 512; off <<= 1) {
        int t = (tid >= off) ? sh[tid - off] : 0;
        __syncthreads();
        sh[tid] += t;
        __syncthreads();
    }
    int incl = sh[tid];
    int excl = incl - v;
    if (tid < nbkt) { bbase[tid] = excl; bcursor[tid] = excl; }
    if (tid == nbkt - 1) bbase[nbkt] = incl;   // = E
}

// 3) scatter edges into bucket-grouped ebuf (packed dst,src)
__global__ void k_bfill(const int* __restrict__ src, const int* __restrict__ dst,
                        int* __restrict__ bcursor, uint2* __restrict__ ebuf, int E) {
    int i = blockIdx.x * blockDim.x + threadIdx.x;
    if (i < E) {
        int d = dst[i];
        int pos = atomicAdd(&bcursor[d >> BSH], 1);
        ebuf[pos] = make_uint2((unsigned)d, (unsigned)src[i]);
    }
}

// 4) per-bucket counting sort -> csr, row_ptr, row_end, inv_deg
__global__ void k_bsort(const uint2* __restrict__ ebuf, const int* __restrict__ bbase,
                        int* __restrict__ csr, int* __restrict__ rp, int* __restrict__ re,
                        float* __restrict__ invd, int n) {
    __shared__ int cnt[BNODES];
    __shared__ int cur[BNODES];
    const int b = blockIdx.x;
    const int tid = threadIdx.x;
    const int lo = bbase[b], hi = bbase[b + 1];
    if (tid < BNODES) cnt[tid] = 0;
    __syncthreads();
    for (int i = lo + tid; i < hi; i += blockDim.x)
        atomicAdd(&cnt[(int)ebuf[i].x - (b << BSH)], 1);
    __syncthreads();
    int v = (tid < BNODES) ? cnt[tid] : 0;
    for (int off = 1; off < BNODES; off <<= 1) {
        int t = (tid < BNODES && tid >= off) ? cnt[tid - off] : 0;
        __syncthreads();
        if (tid < BNODES) cnt[tid] += t;
        __syncthreads();
    }
    if (tid < BNODES) {
        int excl = cnt[tid] - v;
        int node = (b << BSH) + tid;
        if (node < n) {
            rp[node] = lo + excl;
            re[node] = lo + excl + v;
            invd[node] = (v > 0) ? (1.0f / (float)v) : 0.f;
        }
        cur[tid] = excl;
    }
    __syncthreads();
    for (int i = lo + tid; i < hi; i += blockDim.x) {
        uint2 e2 = ebuf[i];
        int local = (int)e2.x - (b << BSH);
        int p = lo + atomicAdd(&cur[local], 1);
        csr[p] = (int)e2.y;
    }
}

// ---------------- fp32 -> bf16 feature convert ----------------

__global__ void k_cvt(const float4* __restrict__ in, uint4* __restrict__ o, int n16) {
    int i = blockIdx.x * blockDim.x + threadIdx.x;
    if (i >= n16) return;
    float4 x = in[2 * i], y = in[2 * i + 1];
    uint4 r;
    r.x = (unsigned)f2bf(x.x) | ((unsigned)f2bf(x.y) << 16);
    r.y = (unsigned)f2bf(x.z) | ((unsigned)f2bf(x.w) << 16);
    r.z = (unsigned)f2bf(y.x) | ((unsigned)f2bf(y.y) << 16);
    r.w = (unsigned)f2bf(y.z) | ((unsigned)f2bf(y.w) << 16);
    o[i] = r;
}

// ---------------- W (96x96 fp32, [k][f]) -> Wt (bf16, [f][k]) ----------------

__global__ void k_wprep(const float* __restrict__ W, unsigned short* __restrict__ Wt) {
    int i = blockIdx.x * blockDim.x + threadIdx.x;   // i = k*96 + col
    if (i >= FD * FD) return;
    int col = i % FD, k = i / FD;
    Wt[col * FD + k] = f2bf(W[i]);
}

// ---------------- aggregation: t = nrm(self) + inv_deg * sum nrm(nbr), bf16 io ----------------

template<int NORM>
__global__ __launch_bounds__(256, 4) void k_agg(
    const uint4* __restrict__ h,      // bf16 rows, NB12 uint4 each
    const int* __restrict__ rp, const int* __restrict__ re,
    const int* __restrict__ csr, const float* __restrict__ invd,
    const float* __restrict__ nA, const float* __restrict__ nC,
    uint4* __restrict__ t, int n)
{
    int g = blockIdx.x * blockDim.x + threadIdx.x;
    int node = g / NB12;
    if (node >= n) return;
    int q = g - node * NB12;
    float a[8], c[8];
    if (NORM) {
        #pragma unroll
        for (int z = 0; z < 8; z++) { a[z] = nA[q * 8 + z]; c[z] = nC[q * 8 + z]; }
    }
    float acc8[8];
    #pragma unroll
    for (int z = 0; z < 8; z++) acc8[z] = 0.f;

    int e = rp[node];
    const int end = re[node];
    for (; e + 8 <= end; e += 8) {
        uint4 raw[8];
        #pragma unroll
        for (int u = 0; u < 8; u++) raw[u] = h[(size_t)csr[e + u] * NB12 + q];
        #pragma unroll
        for (int u = 0; u < 8; u++) {
            float v[8];
            v[0] = bflo(raw[u].x); v[1] = bfhi(raw[u].x);
            v[2] = bflo(raw[u].y); v[3] = bfhi(raw[u].y);
            v[4] = bflo(raw[u].z); v[5] = bfhi(raw[u].z);
            v[6] = bflo(raw[u].w); v[7] = bfhi(raw[u].w);
            #pragma unroll
            for (int z = 0; z < 8; z++) {
                float x = v[z];
                if (NORM) x = fmaxf(fmaf(a[z], x, c[z]), 0.f);
                acc8[z] += x;
            }
        }
    }
    for (; e < end; e++) {
        uint4 raw = h[(size_t)csr[e] * NB12 + q];
        float v[8];
        v[0] = bflo(raw.x); v[1] = bfhi(raw.x);
        v[2] = bflo(raw.y); v[3] = bfhi(raw.y);
        v[4] = bflo(raw.z); v[5] = bfhi(raw.z);
        v[6] = bflo(raw.w); v[7] = bfhi(raw.w);
        #pragma unroll
        for (int z = 0; z < 8; z++) {
            float x = v[z];
            if (NORM) x = fmaxf(fmaf(a[z], x, c[z]), 0.f);
            acc8[z] += x;
        }
    }
    uint4 rs = h[(size_t)node * NB12 + q];
    float xs[8];
    xs[0] = bflo(rs.x); xs[1] = bfhi(rs.x);
    xs[2] = bflo(rs.y); xs[3] = bfhi(rs.y);
    xs[4] = bflo(rs.z); xs[5] = bfhi(rs.z);
    xs[6] = bflo(rs.w); xs[7] = bfhi(rs.w);
    float id = invd[node];
    float o[8];
    #pragma unroll
    for (int z = 0; z < 8; z++) {
        float x = xs[z];
        if (NORM) x = fmaxf(fmaf(a[z], x, c[z]), 0.f);
        o[z] = fmaf(id, acc8[z], x);
    }
    uint4 pk;
    pk.x = (unsigned)f2bf(o[0]) | ((unsigned)f2bf(o[1]) << 16);
    pk.y = (unsigned)f2bf(o[2]) | ((unsigned)f2bf(o[3]) << 16);
    pk.z = (unsigned)f2bf(o[4]) | ((unsigned)f2bf(o[5]) << 16);
    pk.w = (unsigned)f2bf(o[6]) | ((unsigned)f2bf(o[7]) << 16);
    t[(size_t)node * NB12 + q] = pk;
}

// ---------------- MFMA matmul: y = t @ W + b ----------------

template<int STATS, int OBF>
__global__ void k_mm(const unsigned short* __restrict__ ta,
                     const unsigned short* __restrict__ Wt,
                     const float* __restrict__ bias,
                     unsigned short* __restrict__ yb, float* __restrict__ yf,
                     float* __restrict__ accg, int n)
{
    __shared__ float sred[2 * FD];
    const int tid  = threadIdx.x;
    const int lane = tid & 63;
    const int wv   = tid >> 6;
    const int colb = lane & 15;
    const int hg   = lane >> 4;
    const int rbase = blockIdx.x * 64 + wv * 16;
    const int r = rbase + colb;

    s16x8 a[3];
    if (r < n) {
        #pragma unroll
        for (int s = 0; s < 3; s++)
            a[s] = *reinterpret_cast<const s16x8*>(ta + (size_t)r * FD + s * 32 + hg * 8);
    } else {
        #pragma unroll
        for (int s = 0; s < 3; s++) a[s] = s16x8{0, 0, 0, 0, 0, 0, 0, 0};
    }
    s16x8 b[6][3];
    #pragma unroll
    for (int c2 = 0; c2 < 6; c2++)
        #pragma unroll
        for (int s = 0; s < 3; s++)
            b[c2][s] = *reinterpret_cast<const s16x8*>(Wt + (size_t)(c2 * 16 + colb) * FD + s * 32 + hg * 8);

    f32x4 acc[6];
    #pragma unroll
    for (int c2 = 0; c2 < 6; c2++) acc[c2] = (f32x4){0.f, 0.f, 0.f, 0.f};
    #pragma unroll
    for (int s = 0; s < 3; s++)
        #pragma unroll
        for (int c2 = 0; c2 < 6; c2++)
            acc[c2] = __builtin_amdgcn_mfma_f32_16x16x32_bf16(a[s], b[c2][s], acc[c2], 0, 0, 0);

    float s1[6], s2[6];
    #pragma unroll
    for (int c2 = 0; c2 < 6; c2++) { s1[c2] = 0.f; s2[c2] = 0.f; }
    #pragma unroll
    for (int c2 = 0; c2 < 6; c2++) {
        float bc = bias[c2 * 16 + colb];
        #pragma unroll
        for (int j = 0; j < 4; j++) {
            int rr = rbase + hg * 4 + j;
            if (rr < n) {
                float y = acc[c2][j] + bc;
                if (OBF) yb[(size_t)rr * FD + c2 * 16 + colb] = f2bf(y);
                else     yf[(size_t)rr * FD + c2 * 16 + colb] = y;
                if (STATS) { s1[c2] += y; s2[c2] = fmaf(y, y, s2[c2]); }
            }
        }
    }
    if (STATS) {
        if (tid < 2 * FD) sred[tid] = 0.f;
        __syncthreads();
        #pragma unroll
        for (int c2 = 0; c2 < 6; c2++) {
            float v1 = s1[c2], v2 = s2[c2];
            v1 += __shfl_xor(v1, 16, 64); v1 += __shfl_xor(v1, 32, 64);
            v2 += __shfl_xor(v2, 16, 64); v2 += __shfl_xor(v2, 32, 64);
            if (lane < 16) {
                atomicAdd(&sred[c2 * 16 + colb], v1);
                atomicAdd(&sred[FD + c2 * 16 + colb], v2);
            }
        }
        __syncthreads();
        if (tid < 2 * FD) atomicAdd(&accg[tid], sred[tid]);
    }
}

// BN constants: a = gamma*rsqrt(var+eps), c = beta - mu*a
__global__ void k_bnfin(const float* __restrict__ acc,
                        const float* __restrict__ gamma, const float* __restrict__ beta,
                        float* __restrict__ na, float* __restrict__ nc, float invN) {
    int f = threadIdx.x;
    float mu  = acc[f] * invN;
    float var = acc[FD + f] * invN - mu * mu;
    float a = gamma[f] * rsqrtf(var + 1e-5f);
    na[f] = a;
    nc[f] = beta[f] - mu * a;
}

extern "C" void kernel_launch(void* const* d_in, const int* in_sizes, int n_in,
                              void* d_out, int out_size, void* d_ws, size_t ws_size,
                              hipStream_t stream) {
    const float* feat = (const float*)d_in[0];
    const float* W1   = (const float*)d_in[1];
    const float* b1   = (const float*)d_in[2];
    const float* g1   = (const float*)d_in[3];
    const float* be1  = (const float*)d_in[4];
    const float* W2   = (const float*)d_in[5];
    const float* b2   = (const float*)d_in[6];
    const float* g2   = (const float*)d_in[7];
    const float* be2  = (const float*)d_in[8];
    const float* W3   = (const float*)d_in[9];
    const float* b3   = (const float*)d_in[10];
    const int*   src  = (const int*)d_in[11];
    const int*   dst  = (const int*)d_in[12];

    const int n = in_sizes[0] / FD;   // 50000
    const int e = in_sizes[11];       // 800000
    const int nbkt = (n + BNODES - 1) >> BSH;   // 391

    char* w = (char*)d_ws;
    unsigned short* hf0 = (unsigned short*)w; w += (size_t)n * FD * 2;   // features bf16
    unsigned short* tb  = (unsigned short*)w; w += (size_t)n * FD * 2;   // t buffer bf16 (aliases ebuf)
    unsigned short* Wt1 = (unsigned short*)w; w += FD * FD * 2;
    unsigned short* Wt2 = (unsigned short*)w; w += FD * FD * 2;
    unsigned short* Wt3 = (unsigned short*)w; w += FD * FD * 2;
    int*   csr     = (int*)w;   w += (size_t)e * 4;
    int*   bcnt    = (int*)w;   w += 512 * 4;          // zeroed
    float* acc1    = (float*)w; w += 2 * FD * 4;       // zeroed
    float* acc2    = (float*)w; w += 2 * FD * 4;       // zeroed
    int*   bbase   = (int*)w;   w += 513 * 4;
    int*   bcursor = (int*)w;   w += 512 * 4;
    int*   rp      = (int*)w;   w += (size_t)n * 4;
    int*   re      = (int*)w;   w += (size_t)n * 4;
    float* invd    = (float*)w; w += (size_t)n * 4;
    float* na1     = (float*)w; w += FD * 4;
    float* nc1     = (float*)w; w += FD * 4;
    float* na2     = (float*)w; w += FD * 4;
    float* nc2     = (float*)w; w += FD * 4;

    uint2* ebuf = (uint2*)tb;   // dead before first k_agg writes tb

    unsigned short* yb = (unsigned short*)d_out;   // bf16 y lives inside d_out
    float* O = (float*)d_out;
    const float invN = 1.0f / (float)n;
    const int AGG_GRID = (n * NB12 + 255) / 256;
    const int MM_GRID  = (n + 63) / 64;
    const int n16 = n * FD / 8;

    hipMemsetAsync(bcnt, 0, (512 + 4 * FD) * 4, stream);
    k_cvt<<<(n16 + 255) / 256, 256, 0, stream>>>((const float4*)feat, (uint4*)hf0, n16);
    k_wprep<<<(FD * FD + 255) / 256, 256, 0, stream>>>(W1, Wt1);
    k_wprep<<<(FD * FD + 255) / 256, 256, 0, stream>>>(W2, Wt2);
    k_wprep<<<(FD * FD + 255) / 256, 256, 0, stream>>>(W3, Wt3);

    k_bcount<<<128, 512, 0, stream>>>(dst, bcnt, e, nbkt);
    k_bscan<<<1, 512, 0, stream>>>(bcnt, bbase, bcursor, nbkt);
    k_bfill<<<(e + 255) / 256, 256, 0, stream>>>(src, dst, bcursor, ebuf, e);
    k_bsort<<<nbkt, 256, 0, stream>>>(ebuf, bbase, csr, rp, re, invd, n);

    // layer 1
    k_agg<0><<<AGG_GRID, 256, 0, stream>>>((const uint4*)hf0, rp, re, csr, invd,
                                           nullptr, nullptr, (uint4*)tb, n);
    k_mm<1, 1><<<MM_GRID, 256, 0, stream>>>(tb, Wt1, b1, yb, nullptr, acc1, n);
    k_bnfin<<<1, FD, 0, stream>>>(acc1, g1, be1, na1, nc1, invN);

    // layer 2
    k_agg<1><<<AGG_GRID, 256, 0, stream>>>((const uint4*)yb, rp, re, csr, invd,
                                           na1, nc1, (uint4*)tb, n);
    k_mm<1, 1><<<MM_GRID, 256, 0, stream>>>(tb, Wt2, b2, yb, nullptr, acc2, n);
    k_bnfin<<<1, FD, 0, stream>>>(acc2, g2, be2, na2, nc2, invN);

    // layer 3
    k_agg<1><<<AGG_GRID, 256, 0, stream>>>((const uint4*)yb, rp, re, csr, invd,
                                           na2, nc2, (uint4*)tb, n);
    k_mm<0, 0><<<MM_GRID, 256, 0, stream>>>(tb, Wt3, b3, nullptr, O, nullptr, n);
}

// Round 9
// 237.543 us; speedup vs baseline: 2.0988x; 2.0988x over previous
//
#include <hip/hip_runtime.h>

#define FD 96
#define NB12 12     // 16B (8-elem bf16) chunks per row
#define BSH 7       // 128 nodes per bucket
#define BNODES 128
#define NBLK 256    // blocks for 2D-histogram scatter

typedef float  f32x4 __attribute__((ext_vector_type(4)));
typedef short  s16x8 __attribute__((ext_vector_type(8)));

__device__ __forceinline__ unsigned short f2bf(float x) {
    unsigned u = __float_as_uint(x);
    u = (u + 0x7fffu + ((u >> 16) & 1u)) >> 16;
    return (unsigned short)u;
}
__device__ __forceinline__ float bflo(unsigned u) { return __uint_as_float(u << 16); }
__device__ __forceinline__ float bfhi(unsigned u) { return __uint_as_float(u & 0xffff0000u); }

// ---------------- bucketed CSR build (contention-free) ----------------

// global bucket histogram (LDS-aggregated)
__global__ void k_bcount(const int* __restrict__ dst, int* __restrict__ bcnt, int E, int nbkt) {
    __shared__ int hist[512];
    int tid = threadIdx.x;
    if (tid < 512) hist[tid] = 0;
    __syncthreads();
    for (int i = blockIdx.x * blockDim.x + tid; i < E; i += gridDim.x * blockDim.x)
        atomicAdd(&hist[dst[i] >> BSH], 1);
    __syncthreads();
    if (tid < nbkt && hist[tid]) atomicAdd(&bcnt[tid], hist[tid]);
}

// exclusive scan over bucket counts (1 block, 512 threads)
__global__ void k_bscan(const int* __restrict__ bcnt, int* __restrict__ bbase, int nbkt) {
    __shared__ int sh[512];
    int tid = threadIdx.x;
    int v = (tid < nbkt) ? bcnt[tid] : 0;
    sh[tid] = v;
    __syncthreads();
    for (int off = 1; off < 512; off <<= 1) {
        int t = (tid >= off) ? sh[tid - off] : 0;
        __syncthreads();
        sh[tid] += t;
        __syncthreads();
    }
    int incl = sh[tid];
    if (tid < nbkt) bbase[tid] = incl - v;
    if (tid == nbkt - 1) bbase[nbkt] = incl;   // = E
}

// per-(block,bucket) histogram, stored transposed: hist2d[q*NBLK + b]
__global__ void k_h2d(const int* __restrict__ dst, int* __restrict__ hist2d,
                      int E, int nbkt, int chunk) {
    __shared__ int hist[512];
    int tid = threadIdx.x, b = blockIdx.x;
    for (int i = tid; i < 512; i += 256) hist[i] = 0;
    __syncthreads();
    int lo = b * chunk, hi = min(lo + chunk, E);
    for (int i = lo + tid; i < hi; i += 256)
        atomicAdd(&hist[dst[i] >> BSH], 1);
    __syncthreads();
    for (int q = tid; q < nbkt; q += 256)
        hist2d[(size_t)q * NBLK + b] = hist[q];
}

// column scan: cursor2d[q][b] = bbase[q] + sum_{b'<b} hist2d[q][b']
__global__ void k_cscan(const int* __restrict__ hist2d, const int* __restrict__ bbase,
                        int* __restrict__ cursor2d) {
    __shared__ int sh[NBLK];
    int q = blockIdx.x, tid = threadIdx.x;
    int v = hist2d[(size_t)q * NBLK + tid];
    sh[tid] = v;
    __syncthreads();
    for (int off = 1; off < NBLK; off <<= 1) {
        int t = (tid >= off) ? sh[tid - off] : 0;
        __syncthreads();
        sh[tid] += t;
        __syncthreads();
    }
    cursor2d[(size_t)q * NBLK + tid] = bbase[q] + sh[tid] - v;
}

// scatter into bucket-grouped ebuf using private per-(block,bucket) ranges; LDS atomics only
__global__ void k_scat(const int* __restrict__ src, const int* __restrict__ dst,
                       const int* __restrict__ cursor2d, uint2* __restrict__ ebuf,
                       int E, int nbkt, int chunk) {
    __shared__ int cur[512];
    int tid = threadIdx.x, b = blockIdx.x;
    for (int q = tid; q < nbkt; q += 256)
        cur[q] = cursor2d[(size_t)q * NBLK + b];
    __syncthreads();
    int lo = b * chunk, hi = min(lo + chunk, E);
    for (int i = lo + tid; i < hi; i += 256) {
        int d = dst[i];
        int p = atomicAdd(&cur[d >> BSH], 1);
        ebuf[p] = make_uint2((unsigned)d, (unsigned)src[i]);
    }
}

// per-bucket counting sort -> csr, row_ptr, row_end, inv_deg
__global__ void k_bsort(const uint2* __restrict__ ebuf, const int* __restrict__ bbase,
                        int* __restrict__ csr, int* __restrict__ rp, int* __restrict__ re,
                        float* __restrict__ invd, int n) {
    __shared__ int cnt[BNODES];
    __shared__ int cur[BNODES];
    const int b = blockIdx.x;
    const int tid = threadIdx.x;
    const int lo = bbase[b], hi = bbase[b + 1];
    if (tid < BNODES) cnt[tid] = 0;
    __syncthreads();
    for (int i = lo + tid; i < hi; i += blockDim.x)
        atomicAdd(&cnt[(int)ebuf[i].x - (b << BSH)], 1);
    __syncthreads();
    int v = (tid < BNODES) ? cnt[tid] : 0;
    for (int off = 1; off < BNODES; off <<= 1) {
        int t = (tid < BNODES && tid >= off) ? cnt[tid - off] : 0;
        __syncthreads();
        if (tid < BNODES) cnt[tid] += t;
        __syncthreads();
    }
    if (tid < BNODES) {
        int excl = cnt[tid] - v;
        int node = (b << BSH) + tid;
        if (node < n) {
            rp[node] = lo + excl;
            re[node] = lo + excl + v;
            invd[node] = (v > 0) ? (1.0f / (float)v) : 0.f;
        }
        cur[tid] = excl;
    }
    __syncthreads();
    for (int i = lo + tid; i < hi; i += blockDim.x) {
        uint2 e2 = ebuf[i];
        int local = (int)e2.x - (b << BSH);
        int p = lo + atomicAdd(&cur[local], 1);
        csr[p] = (int)e2.y;
    }
}

// ---------------- fp32 -> bf16 feature convert ----------------

__global__ void k_cvt(const float4* __restrict__ in, uint4* __restrict__ o, int n16) {
    int i = blockIdx.x * blockDim.x + threadIdx.x;
    if (i >= n16) return;
    float4 x = in[2 * i], y = in[2 * i + 1];
    uint4 r;
    r.x = (unsigned)f2bf(x.x) | ((unsigned)f2bf(x.y) << 16);
    r.y = (unsigned)f2bf(x.z) | ((unsigned)f2bf(x.w) << 16);
    r.z = (unsigned)f2bf(y.x) | ((unsigned)f2bf(y.y) << 16);
    r.w = (unsigned)f2bf(y.z) | ((unsigned)f2bf(y.w) << 16);
    o[i] = r;
}

// ---------------- W (96x96 fp32, [k][f]) -> Wt (bf16, [f][k]) ----------------

__global__ void k_wprep(const float* __restrict__ W, unsigned short* __restrict__ Wt) {
    int i = blockIdx.x * blockDim.x + threadIdx.x;   // i = k*96 + col
    if (i >= FD * FD) return;
    int col = i % FD, k = i / FD;
    Wt[col * FD + k] = f2bf(W[i]);
}

// ---------------- aggregation: t = nrm(self) + inv_deg * sum nrm(nbr), bf16 io ----------------

template<int NORM>
__global__ __launch_bounds__(256, 4) void k_agg(
    const uint4* __restrict__ h,
    const int* __restrict__ rp, const int* __restrict__ re,
    const int* __restrict__ csr, const float* __restrict__ invd,
    const float* __restrict__ nA, const float* __restrict__ nC,
    uint4* __restrict__ t, int n)
{
    int g = blockIdx.x * blockDim.x + threadIdx.x;
    int node = g / NB12;
    if (node >= n) return;
    int q = g - node * NB12;
    float a[8], c[8];
    if (NORM) {
        #pragma unroll
        for (int z = 0; z < 8; z++) { a[z] = nA[q * 8 + z]; c[z] = nC[q * 8 + z]; }
    }
    float acc8[8];
    #pragma unroll
    for (int z = 0; z < 8; z++) acc8[z] = 0.f;

    int e = rp[node];
    const int end = re[node];
    for (; e + 8 <= end; e += 8) {
        uint4 raw[8];
        #pragma unroll
        for (int u = 0; u < 8; u++) raw[u] = h[(size_t)csr[e + u] * NB12 + q];
        #pragma unroll
        for (int u = 0; u < 8; u++) {
            float v[8];
            v[0] = bflo(raw[u].x); v[1] = bfhi(raw[u].x);
            v[2] = bflo(raw[u].y); v[3] = bfhi(raw[u].y);
            v[4] = bflo(raw[u].z); v[5] = bfhi(raw[u].z);
            v[6] = bflo(raw[u].w); v[7] = bfhi(raw[u].w);
            #pragma unroll
            for (int z = 0; z < 8; z++) {
                float x = v[z];
                if (NORM) x = fmaxf(fmaf(a[z], x, c[z]), 0.f);
                acc8[z] += x;
            }
        }
    }
    for (; e < end; e++) {
        uint4 raw = h[(size_t)csr[e] * NB12 + q];
        float v[8];
        v[0] = bflo(raw.x); v[1] = bfhi(raw.x);
        v[2] = bflo(raw.y); v[3] = bfhi(raw.y);
        v[4] = bflo(raw.z); v[5] = bfhi(raw.z);
        v[6] = bflo(raw.w); v[7] = bfhi(raw.w);
        #pragma unroll
        for (int z = 0; z < 8; z++) {
            float x = v[z];
            if (NORM) x = fmaxf(fmaf(a[z], x, c[z]), 0.f);
            acc8[z] += x;
        }
    }
    uint4 rs = h[(size_t)node * NB12 + q];
    float xs[8];
    xs[0] = bflo(rs.x); xs[1] = bfhi(rs.x);
    xs[2] = bflo(rs.y); xs[3] = bfhi(rs.y);
    xs[4] = bflo(rs.z); xs[5] = bfhi(rs.z);
    xs[6] = bflo(rs.w); xs[7] = bfhi(rs.w);
    float id = invd[node];
    float o[8];
    #pragma unroll
    for (int z = 0; z < 8; z++) {
        float x = xs[z];
        if (NORM) x = fmaxf(fmaf(a[z], x, c[z]), 0.f);
        o[z] = fmaf(id, acc8[z], x);
    }
    uint4 pk;
    pk.x = (unsigned)f2bf(o[0]) | ((unsigned)f2bf(o[1]) << 16);
    pk.y = (unsigned)f2bf(o[2]) | ((unsigned)f2bf(o[3]) << 16);
    pk.z = (unsigned)f2bf(o[4]) | ((unsigned)f2bf(o[5]) << 16);
    pk.w = (unsigned)f2bf(o[6]) | ((unsigned)f2bf(o[7]) << 16);
    t[(size_t)node * NB12 + q] = pk;
}

// ---------------- MFMA matmul: y = t @ W + b ----------------

template<int STATS, int OBF>
__global__ void k_mm(const unsigned short* __restrict__ ta,
                     const unsigned short* __restrict__ Wt,
                     const float* __restrict__ bias,
                     unsigned short* __restrict__ yb, float* __restrict__ yf,
                     float* __restrict__ accg, int n)
{
    __shared__ float sred[2 * FD];
    const int tid  = threadIdx.x;
    const int lane = tid & 63;
    const int wv   = tid >> 6;
    const int colb = lane & 15;
    const int hg   = lane >> 4;
    const int rbase = blockIdx.x * 64 + wv * 16;
    const int r = rbase + colb;

    s16x8 a[3];
    if (r < n) {
        #pragma unroll
        for (int s = 0; s < 3; s++)
            a[s] = *reinterpret_cast<const s16x8*>(ta + (size_t)r * FD + s * 32 + hg * 8);
    } else {
        #pragma unroll
        for (int s = 0; s < 3; s++) a[s] = s16x8{0, 0, 0, 0, 0, 0, 0, 0};
    }
    s16x8 b[6][3];
    #pragma unroll
    for (int c2 = 0; c2 < 6; c2++)
        #pragma unroll
        for (int s = 0; s < 3; s++)
            b[c2][s] = *reinterpret_cast<const s16x8*>(Wt + (size_t)(c2 * 16 + colb) * FD + s * 32 + hg * 8);

    f32x4 acc[6];
    #pragma unroll
    for (int c2 = 0; c2 < 6; c2++) acc[c2] = (f32x4){0.f, 0.f, 0.f, 0.f};
    #pragma unroll
    for (int s = 0; s < 3; s++)
        #pragma unroll
        for (int c2 = 0; c2 < 6; c2++)
            acc[c2] = __builtin_amdgcn_mfma_f32_16x16x32_bf16(a[s], b[c2][s], acc[c2], 0, 0, 0);

    float s1[6], s2[6];
    #pragma unroll
    for (int c2 = 0; c2 < 6; c2++) { s1[c2] = 0.f; s2[c2] = 0.f; }
    #pragma unroll
    for (int c2 = 0; c2 < 6; c2++) {
        float bc = bias[c2 * 16 + colb];
        #pragma unroll
        for (int j = 0; j < 4; j++) {
            int rr = rbase + hg * 4 + j;
            if (rr < n) {
                float y = acc[c2][j] + bc;
                if (OBF) yb[(size_t)rr * FD + c2 * 16 + colb] = f2bf(y);
                else     yf[(size_t)rr * FD + c2 * 16 + colb] = y;
                if (STATS) { s1[c2] += y; s2[c2] = fmaf(y, y, s2[c2]); }
            }
        }
    }
    if (STATS) {
        if (tid < 2 * FD) sred[tid] = 0.f;
        __syncthreads();
        #pragma unroll
        for (int c2 = 0; c2 < 6; c2++) {
            float v1 = s1[c2], v2 = s2[c2];
            v1 += __shfl_xor(v1, 16, 64); v1 += __shfl_xor(v1, 32, 64);
            v2 += __shfl_xor(v2, 16, 64); v2 += __shfl_xor(v2, 32, 64);
            if (lane < 16) {
                atomicAdd(&sred[c2 * 16 + colb], v1);
                atomicAdd(&sred[FD + c2 * 16 + colb], v2);
            }
        }
        __syncthreads();
        if (tid < 2 * FD) atomicAdd(&accg[tid], sred[tid]);
    }
}

// BN constants: a = gamma*rsqrt(var+eps), c = beta - mu*a
__global__ void k_bnfin(const float* __restrict__ acc,
                        const float* __restrict__ gamma, const float* __restrict__ beta,
                        float* __restrict__ na, float* __restrict__ nc, float invN) {
    int f = threadIdx.x;
    float mu  = acc[f] * invN;
    float var = acc[FD + f] * invN - mu * mu;
    float a = gamma[f] * rsqrtf(var + 1e-5f);
    na[f] = a;
    nc[f] = beta[f] - mu * a;
}

extern "C" void kernel_launch(void* const* d_in, const int* in_sizes, int n_in,
                              void* d_out, int out_size, void* d_ws, size_t ws_size,
                              hipStream_t stream) {
    const float* feat = (const float*)d_in[0];
    const float* W1   = (const float*)d_in[1];
    const float* b1   = (const float*)d_in[2];
    const float* g1   = (const float*)d_in[3];
    const float* be1  = (const float*)d_in[4];
    const float* W2   = (const float*)d_in[5];
    const float* b2   = (const float*)d_in[6];
    const float* g2   = (const float*)d_in[7];
    const float* be2  = (const float*)d_in[8];
    const float* W3   = (const float*)d_in[9];
    const float* b3   = (const float*)d_in[10];
    const int*   src  = (const int*)d_in[11];
    const int*   dst  = (const int*)d_in[12];

    const int n = in_sizes[0] / FD;   // 50000
    const int e = in_sizes[11];       // 800000
    const int nbkt = (n + BNODES - 1) >> BSH;     // 391
    const int chunk = (e + NBLK - 1) / NBLK;      // 3125

    char* w = (char*)d_ws;
    unsigned short* hf0 = (unsigned short*)w; w += (size_t)n * FD * 2;   // features bf16
    unsigned short* tb  = (unsigned short*)w; w += (size_t)n * FD * 2;   // t buffer bf16 (aliases ebuf)
    unsigned short* Wt1 = (unsigned short*)w; w += FD * FD * 2;
    unsigned short* Wt2 = (unsigned short*)w; w += FD * FD * 2;
    unsigned short* Wt3 = (unsigned short*)w; w += FD * FD * 2;
    int*   csr     = (int*)w;   w += (size_t)e * 4;
    int*   bcnt    = (int*)w;   w += 512 * 4;          // zeroed
    float* acc1    = (float*)w; w += 2 * FD * 4;       // zeroed
    float* acc2    = (float*)w; w += 2 * FD * 4;       // zeroed
    int*   bbase   = (int*)w;   w += 513 * 4;
    int*   hist2d  = (int*)w;   w += (size_t)512 * NBLK * 4;
    int*   cursor2d= (int*)w;   w += (size_t)512 * NBLK * 4;
    int*   rp      = (int*)w;   w += (size_t)n * 4;
    int*   re      = (int*)w;   w += (size_t)n * 4;
    float* invd    = (float*)w; w += (size_t)n * 4;
    float* na1     = (float*)w; w += FD * 4;
    float* nc1     = (float*)w; w += FD * 4;
    float* na2     = (float*)w; w += FD * 4;
    float* nc2     = (float*)w; w += FD * 4;

    uint2* ebuf = (uint2*)tb;   // dead until first k_agg writes tb

    unsigned short* yb = (unsigned short*)d_out;
    float* O = (float*)d_out;
    const float invN = 1.0f / (float)n;
    const int AGG_GRID = (n * NB12 + 255) / 256;
    const int MM_GRID  = (n + 63) / 64;
    const int n16 = n * FD / 8;

    hipMemsetAsync(bcnt, 0, (512 + 4 * FD) * 4, stream);
    k_cvt<<<(n16 + 255) / 256, 256, 0, stream>>>((const float4*)feat, (uint4*)hf0, n16);
    k_wprep<<<(FD * FD + 255) / 256, 256, 0, stream>>>(W1, Wt1);
    k_wprep<<<(FD * FD + 255) / 256, 256, 0, stream>>>(W2, Wt2);
    k_wprep<<<(FD * FD + 255) / 256, 256, 0, stream>>>(W3, Wt3);

    k_bcount<<<128, 512, 0, stream>>>(dst, bcnt, e, nbkt);
    k_bscan<<<1, 512, 0, stream>>>(bcnt, bbase, nbkt);
    k_h2d<<<NBLK, 256, 0, stream>>>(dst, hist2d, e, nbkt, chunk);
    k_cscan<<<nbkt, NBLK, 0, stream>>>(hist2d, bbase, cursor2d);
    k_scat<<<NBLK, 256, 0, stream>>>(src, dst, cursor2d, ebuf, e, nbkt, chunk);
    k_bsort<<<nbkt, 256, 0, stream>>>(ebuf, bbase, csr, rp, re, invd, n);

    // layer 1
    k_agg<0><<<AGG_GRID, 256, 0, stream>>>((const uint4*)hf0, rp, re, csr, invd,
                                           nullptr, nullptr, (uint4*)tb, n);
    k_mm<1, 1><<<MM_GRID, 256, 0, stream>>>(tb, Wt1, b1, yb, nullptr, acc1, n);
    k_bnfin<<<1, FD, 0, stream>>>(acc1, g1, be1, na1, nc1, invN);

    // layer 2
    k_agg<1><<<AGG_GRID, 256, 0, stream>>>((const uint4*)yb, rp, re, csr, invd,
                                           na1, nc1, (uint4*)tb, n);
    k_mm<1, 1><<<MM_GRID, 256, 0, stream>>>(tb, Wt2, b2, yb, nullptr, acc2, n);
    k_bnfin<<<1, FD, 0, stream>>>(acc2, g2, be2, na2, nc2, invN);

    // layer 3
    k_agg<1><<<AGG_GRID, 256, 0, stream>>>((const uint4*)yb, rp, re, csr, invd,
                                           na2, nc2, (uint4*)tb, n);
    k_mm<0, 0><<<MM_GRID, 256, 0, stream>>>(tb, Wt3, b3, nullptr, O, nullptr, n);
}

// Round 10
// 232.119 us; speedup vs baseline: 2.1479x; 1.0234x over previous
//
#include <hip/hip_runtime.h>

#define FD 96
#define NB12 12     // 16B (8-elem bf16) chunks per row
#define BSH 7       // 128 nodes per bucket
#define BNODES 128
#define NBLK 256    // blocks for 2D-histogram scatter

typedef float  f32x4 __attribute__((ext_vector_type(4)));
typedef short  s16x8 __attribute__((ext_vector_type(8)));

__device__ __forceinline__ unsigned short f2bf(float x) {
    unsigned u = __float_as_uint(x);
    u = (u + 0x7fffu + ((u >> 16) & 1u)) >> 16;
    return (unsigned short)u;
}
__device__ __forceinline__ float bflo(unsigned u) { return __uint_as_float(u << 16); }
__device__ __forceinline__ float bfhi(unsigned u) { return __uint_as_float(u & 0xffff0000u); }

// ---------------- bucketed CSR build (contention-free) ----------------

// per-(block,bucket) histogram (transposed) + global bucket counts (non-returning atomics)
__global__ void k_h2d(const int* __restrict__ dst, int* __restrict__ hist2d,
                      int* __restrict__ bcnt, int E, int nbkt, int chunk) {
    __shared__ int hist[512];
    int tid = threadIdx.x, b = blockIdx.x;
    for (int i = tid; i < 512; i += 256) hist[i] = 0;
    __syncthreads();
    int lo = b * chunk, hi = min(lo + chunk, E);
    for (int i = lo + tid; i < hi; i += 256)
        atomicAdd(&hist[dst[i] >> BSH], 1);
    __syncthreads();
    for (int q = tid; q < nbkt; q += 256) {
        int hv = hist[q];
        hist2d[(size_t)q * NBLK + b] = hv;
        if (hv) atomicAdd(&bcnt[q], hv);
    }
}

// exclusive scan over bucket counts (1 block, 512 threads)
__global__ void k_bscan(const int* __restrict__ bcnt, int* __restrict__ bbase, int nbkt) {
    __shared__ int sh[512];
    int tid = threadIdx.x;
    int v = (tid < nbkt) ? bcnt[tid] : 0;
    sh[tid] = v;
    __syncthreads();
    for (int off = 1; off < 512; off <<= 1) {
        int t = (tid >= off) ? sh[tid - off] : 0;
        __syncthreads();
        sh[tid] += t;
        __syncthreads();
    }
    int incl = sh[tid];
    if (tid < nbkt) bbase[tid] = incl - v;
    if (tid == nbkt - 1) bbase[nbkt] = incl;   // = E
}

// column scan: cursor2d[q][b] = bbase[q] + sum_{b'<b} hist2d[q][b']
__global__ void k_cscan(const int* __restrict__ hist2d, const int* __restrict__ bbase,
                        int* __restrict__ cursor2d) {
    __shared__ int sh[NBLK];
    int q = blockIdx.x, tid = threadIdx.x;
    int v = hist2d[(size_t)q * NBLK + tid];
    sh[tid] = v;
    __syncthreads();
    for (int off = 1; off < NBLK; off <<= 1) {
        int t = (tid >= off) ? sh[tid - off] : 0;
        __syncthreads();
        sh[tid] += t;
        __syncthreads();
    }
    cursor2d[(size_t)q * NBLK + tid] = bbase[q] + sh[tid] - v;
}

// scatter into bucket-grouped ebuf using private per-(block,bucket) ranges; LDS atomics only
__global__ void k_scat(const int* __restrict__ src, const int* __restrict__ dst,
                       const int* __restrict__ cursor2d, uint2* __restrict__ ebuf,
                       int E, int nbkt, int chunk) {
    __shared__ int cur[512];
    int tid = threadIdx.x, b = blockIdx.x;
    for (int q = tid; q < nbkt; q += 256)
        cur[q] = cursor2d[(size_t)q * NBLK + b];
    __syncthreads();
    int lo = b * chunk, hi = min(lo + chunk, E);
    for (int i = lo + tid; i < hi; i += 256) {
        int d = dst[i];
        int p = atomicAdd(&cur[d >> BSH], 1);
        ebuf[p] = make_uint2((unsigned)d, (unsigned)src[i]);
    }
}

// per-bucket counting sort -> csr, row_ptr, row_end, inv_deg, degree-sorted perm
__global__ void k_bsort(const uint2* __restrict__ ebuf, const int* __restrict__ bbase,
                        int* __restrict__ csr, int* __restrict__ rp, int* __restrict__ re,
                        float* __restrict__ invd, int* __restrict__ perm, int n) {
    __shared__ int cnt[BNODES];
    __shared__ int cur[BNODES];
    __shared__ int dh[64];
    const int b = blockIdx.x;
    const int tid = threadIdx.x;
    const int lo = bbase[b], hi = bbase[b + 1];
    if (tid < BNODES) cnt[tid] = 0;
    if (tid < 64) dh[tid] = 0;
    __syncthreads();
    for (int i = lo + tid; i < hi; i += blockDim.x)
        atomicAdd(&cnt[(int)ebuf[i].x - (b << BSH)], 1);
    __syncthreads();
    const int node = (b << BSH) + tid;
    const int v = (tid < BNODES) ? cnt[tid] : 0;
    const int dcl = min(v, 63);
    if (tid < BNODES && node < n) atomicAdd(&dh[dcl], 1);
    // scan cnt (128) for csr layout
    for (int off = 1; off < BNODES; off <<= 1) {
        int t = (tid < BNODES && tid >= off) ? cnt[tid - off] : 0;
        __syncthreads();
        if (tid < BNODES) cnt[tid] += t;
        __syncthreads();
    }
    // scan dh (64) -> exclusive bases, then reuse as cursors
    int dv = (tid < 64) ? dh[tid] : 0;
    for (int off = 1; off < 64; off <<= 1) {
        int t = (tid < 64 && tid >= off) ? dh[tid - off] : 0;
        __syncthreads();
        if (tid < 64) dh[tid] += t;
        __syncthreads();
    }
    if (tid < 64) dh[tid] -= dv;
    __syncthreads();
    if (tid < BNODES) {
        int excl = cnt[tid] - v;
        if (node < n) {
            rp[node] = lo + excl;
            re[node] = lo + excl + v;
            invd[node] = (v > 0) ? (1.0f / (float)v) : 0.f;
            int r = atomicAdd(&dh[dcl], 1);
            perm[(b << BSH) + r] = node;   // buckets are dense: slots [b*128, b*128+valid)
        }
        cur[tid] = excl;
    }
    __syncthreads();
    for (int i = lo + tid; i < hi; i += blockDim.x) {
        uint2 e2 = ebuf[i];
        int local = (int)e2.x - (b << BSH);
        int p = lo + atomicAdd(&cur[local], 1);
        csr[p] = (int)e2.y;
    }
}

// ---------------- fp32 -> bf16 feature convert ----------------

__global__ void k_cvt(const float4* __restrict__ in, uint4* __restrict__ o, int n16) {
    int i = blockIdx.x * blockDim.x + threadIdx.x;
    if (i >= n16) return;
    float4 x = in[2 * i], y = in[2 * i + 1];
    uint4 r;
    r.x = (unsigned)f2bf(x.x) | ((unsigned)f2bf(x.y) << 16);
    r.y = (unsigned)f2bf(x.z) | ((unsigned)f2bf(x.w) << 16);
    r.z = (unsigned)f2bf(y.x) | ((unsigned)f2bf(y.y) << 16);
    r.w = (unsigned)f2bf(y.z) | ((unsigned)f2bf(y.w) << 16);
    o[i] = r;
}

// ---------------- W (96x96 fp32, [k][f]) -> Wt (bf16, [f][k]) ----------------

__global__ void k_wprep(const float* __restrict__ W, unsigned short* __restrict__ Wt) {
    int i = blockIdx.x * blockDim.x + threadIdx.x;   // i = k*96 + col
    if (i >= FD * FD) return;
    int col = i % FD, k = i / FD;
    Wt[col * FD + k] = f2bf(W[i]);
}

// ---------------- aggregation: t = nrm(self) + inv_deg * sum nrm(nbr), bf16 io ----------------
// processes nodes in degree-sorted perm order -> near-uniform loop trip count per wave

template<int NORM>
__global__ __launch_bounds__(256, 4) void k_agg(
    const uint4* __restrict__ h,
    const int* __restrict__ rp, const int* __restrict__ re,
    const int* __restrict__ csr, const float* __restrict__ invd,
    const int* __restrict__ perm,
    const float* __restrict__ nA, const float* __restrict__ nC,
    uint4* __restrict__ t, int n)
{
    int g = blockIdx.x * blockDim.x + threadIdx.x;
    int idx = g / NB12;
    if (idx >= n) return;
    int node = perm[idx];
    int q = g - idx * NB12;
    float a[8], c[8];
    if (NORM) {
        #pragma unroll
        for (int z = 0; z < 8; z++) { a[z] = nA[q * 8 + z]; c[z] = nC[q * 8 + z]; }
    }
    float acc8[8];
    #pragma unroll
    for (int z = 0; z < 8; z++) acc8[z] = 0.f;

    int e = rp[node];
    const int end = re[node];
    for (; e + 8 <= end; e += 8) {
        uint4 raw[8];
        #pragma unroll
        for (int u = 0; u < 8; u++) raw[u] = h[(size_t)csr[e + u] * NB12 + q];
        #pragma unroll
        for (int u = 0; u < 8; u++) {
            float v[8];
            v[0] = bflo(raw[u].x); v[1] = bfhi(raw[u].x);
            v[2] = bflo(raw[u].y); v[3] = bfhi(raw[u].y);
            v[4] = bflo(raw[u].z); v[5] = bfhi(raw[u].z);
            v[6] = bflo(raw[u].w); v[7] = bfhi(raw[u].w);
            #pragma unroll
            for (int z = 0; z < 8; z++) {
                float x = v[z];
                if (NORM) x = fmaxf(fmaf(a[z], x, c[z]), 0.f);
                acc8[z] += x;
            }
        }
    }
    for (; e < end; e++) {
        uint4 raw = h[(size_t)csr[e] * NB12 + q];
        float v[8];
        v[0] = bflo(raw.x); v[1] = bfhi(raw.x);
        v[2] = bflo(raw.y); v[3] = bfhi(raw.y);
        v[4] = bflo(raw.z); v[5] = bfhi(raw.z);
        v[6] = bflo(raw.w); v[7] = bfhi(raw.w);
        #pragma unroll
        for (int z = 0; z < 8; z++) {
            float x = v[z];
            if (NORM) x = fmaxf(fmaf(a[z], x, c[z]), 0.f);
            acc8[z] += x;
        }
    }
    uint4 rs = h[(size_t)node * NB12 + q];
    float xs[8];
    xs[0] = bflo(rs.x); xs[1] = bfhi(rs.x);
    xs[2] = bflo(rs.y); xs[3] = bfhi(rs.y);
    xs[4] = bflo(rs.z); xs[5] = bfhi(rs.z);
    xs[6] = bflo(rs.w); xs[7] = bfhi(rs.w);
    float id = invd[node];
    float o[8];
    #pragma unroll
    for (int z = 0; z < 8; z++) {
        float x = xs[z];
        if (NORM) x = fmaxf(fmaf(a[z], x, c[z]), 0.f);
        o[z] = fmaf(id, acc8[z], x);
    }
    uint4 pk;
    pk.x = (unsigned)f2bf(o[0]) | ((unsigned)f2bf(o[1]) << 16);
    pk.y = (unsigned)f2bf(o[2]) | ((unsigned)f2bf(o[3]) << 16);
    pk.z = (unsigned)f2bf(o[4]) | ((unsigned)f2bf(o[5]) << 16);
    pk.w = (unsigned)f2bf(o[6]) | ((unsigned)f2bf(o[7]) << 16);
    t[(size_t)node * NB12 + q] = pk;
}

// ---------------- MFMA matmul: y = t @ W + b ----------------

template<int STATS, int OBF>
__global__ void k_mm(const unsigned short* __restrict__ ta,
                     const unsigned short* __restrict__ Wt,
                     const float* __restrict__ bias,
                     unsigned short* __restrict__ yb, float* __restrict__ yf,
                     float* __restrict__ accg, int n)
{
    __shared__ float sred[2 * FD];
    const int tid  = threadIdx.x;
    const int lane = tid & 63;
    const int wv   = tid >> 6;
    const int colb = lane & 15;
    const int hg   = lane >> 4;
    const int rbase = blockIdx.x * 64 + wv * 16;
    const int r = rbase + colb;

    s16x8 a[3];
    if (r < n) {
        #pragma unroll
        for (int s = 0; s < 3; s++)
            a[s] = *reinterpret_cast<const s16x8*>(ta + (size_t)r * FD + s * 32 + hg * 8);
    } else {
        #pragma unroll
        for (int s = 0; s < 3; s++) a[s] = s16x8{0, 0, 0, 0, 0, 0, 0, 0};
    }
    s16x8 b[6][3];
    #pragma unroll
    for (int c2 = 0; c2 < 6; c2++)
        #pragma unroll
        for (int s = 0; s < 3; s++)
            b[c2][s] = *reinterpret_cast<const s16x8*>(Wt + (size_t)(c2 * 16 + colb) * FD + s * 32 + hg * 8);

    f32x4 acc[6];
    #pragma unroll
    for (int c2 = 0; c2 < 6; c2++) acc[c2] = (f32x4){0.f, 0.f, 0.f, 0.f};
    #pragma unroll
    for (int s = 0; s < 3; s++)
        #pragma unroll
        for (int c2 = 0; c2 < 6; c2++)
            acc[c2] = __builtin_amdgcn_mfma_f32_16x16x32_bf16(a[s], b[c2][s], acc[c2], 0, 0, 0);

    float s1[6], s2[6];
    #pragma unroll
    for (int c2 = 0; c2 < 6; c2++) { s1[c2] = 0.f; s2[c2] = 0.f; }
    #pragma unroll
    for (int c2 = 0; c2 < 6; c2++) {
        float bc = bias[c2 * 16 + colb];
        #pragma unroll
        for (int j = 0; j < 4; j++) {
            int rr = rbase + hg * 4 + j;
            if (rr < n) {
                float y = acc[c2][j] + bc;
                if (OBF) yb[(size_t)rr * FD + c2 * 16 + colb] = f2bf(y);
                else     yf[(size_t)rr * FD + c2 * 16 + colb] = y;
                if (STATS) { s1[c2] += y; s2[c2] = fmaf(y, y, s2[c2]); }
            }
        }
    }
    if (STATS) {
        if (tid < 2 * FD) sred[tid] = 0.f;
        __syncthreads();
        #pragma unroll
        for (int c2 = 0; c2 < 6; c2++) {
            float v1 = s1[c2], v2 = s2[c2];
            v1 += __shfl_xor(v1, 16, 64); v1 += __shfl_xor(v1, 32, 64);
            v2 += __shfl_xor(v2, 16, 64); v2 += __shfl_xor(v2, 32, 64);
            if (lane < 16) {
                atomicAdd(&sred[c2 * 16 + colb], v1);
                atomicAdd(&sred[FD + c2 * 16 + colb], v2);
            }
        }
        __syncthreads();
        if (tid < 2 * FD) atomicAdd(&accg[tid], sred[tid]);
    }
}

// BN constants: a = gamma*rsqrt(var+eps), c = beta - mu*a
__global__ void k_bnfin(const float* __restrict__ acc,
                        const float* __restrict__ gamma, const float* __restrict__ beta,
                        float* __restrict__ na, float* __restrict__ nc, float invN) {
    int f = threadIdx.x;
    float mu  = acc[f] * invN;
    float var = acc[FD + f] * invN - mu * mu;
    float a = gamma[f] * rsqrtf(var + 1e-5f);
    na[f] = a;
    nc[f] = beta[f] - mu * a;
}

extern "C" void kernel_launch(void* const* d_in, const int* in_sizes, int n_in,
                              void* d_out, int out_size, void* d_ws, size_t ws_size,
                              hipStream_t stream) {
    const float* feat = (const float*)d_in[0];
    const float* W1   = (const float*)d_in[1];
    const float* b1   = (const float*)d_in[2];
    const float* g1   = (const float*)d_in[3];
    const float* be1  = (const float*)d_in[4];
    const float* W2   = (const float*)d_in[5];
    const float* b2   = (const float*)d_in[6];
    const float* g2   = (const float*)d_in[7];
    const float* be2  = (const float*)d_in[8];
    const float* W3   = (const float*)d_in[9];
    const float* b3   = (const float*)d_in[10];
    const int*   src  = (const int*)d_in[11];
    const int*   dst  = (const int*)d_in[12];

    const int n = in_sizes[0] / FD;   // 50000
    const int e = in_sizes[11];       // 800000
    const int nbkt = (n + BNODES - 1) >> BSH;     // 391
    const int chunk = (e + NBLK - 1) / NBLK;      // 3125

    char* w = (char*)d_ws;
    unsigned short* hf0 = (unsigned short*)w; w += (size_t)n * FD * 2;   // features bf16
    unsigned short* tb  = (unsigned short*)w; w += (size_t)n * FD * 2;   // t buffer bf16 (aliases ebuf)
    unsigned short* Wt1 = (unsigned short*)w; w += FD * FD * 2;
    unsigned short* Wt2 = (unsigned short*)w; w += FD * FD * 2;
    unsigned short* Wt3 = (unsigned short*)w; w += FD * FD * 2;
    int*   csr     = (int*)w;   w += (size_t)e * 4;
    int*   bcnt    = (int*)w;   w += 512 * 4;          // zeroed
    float* acc1    = (float*)w; w += 2 * FD * 4;       // zeroed
    float* acc2    = (float*)w; w += 2 * FD * 4;       // zeroed
    int*   bbase   = (int*)w;   w += 513 * 4;
    int*   hist2d  = (int*)w;   w += (size_t)512 * NBLK * 4;
    int*   cursor2d= (int*)w;   w += (size_t)512 * NBLK * 4;
    int*   rp      = (int*)w;   w += (size_t)n * 4;
    int*   re      = (int*)w;   w += (size_t)n * 4;
    float* invd    = (float*)w; w += (size_t)n * 4;
    int*   perm    = (int*)w;   w += (size_t)n * 4;
    float* na1     = (float*)w; w += FD * 4;
    float* nc1     = (float*)w; w += FD * 4;
    float* na2     = (float*)w; w += FD * 4;
    float* nc2     = (float*)w; w += FD * 4;

    uint2* ebuf = (uint2*)tb;   // dead until first k_agg writes tb

    unsigned short* yb = (unsigned short*)d_out;
    float* O = (float*)d_out;
    const float invN = 1.0f / (float)n;
    const int AGG_GRID = (n * NB12 + 255) / 256;
    const int MM_GRID  = (n + 63) / 64;
    const int n16 = n * FD / 8;

    hipMemsetAsync(bcnt, 0, (512 + 4 * FD) * 4, stream);
    k_cvt<<<(n16 + 255) / 256, 256, 0, stream>>>((const float4*)feat, (uint4*)hf0, n16);
    k_wprep<<<(FD * FD + 255) / 256, 256, 0, stream>>>(W1, Wt1);
    k_wprep<<<(FD * FD + 255) / 256, 256, 0, stream>>>(W2, Wt2);
    k_wprep<<<(FD * FD + 255) / 256, 256, 0, stream>>>(W3, Wt3);

    k_h2d<<<NBLK, 256, 0, stream>>>(dst, hist2d, bcnt, e, nbkt, chunk);
    k_bscan<<<1, 512, 0, stream>>>(bcnt, bbase, nbkt);
    k_cscan<<<nbkt, NBLK, 0, stream>>>(hist2d, bbase, cursor2d);
    k_scat<<<NBLK, 256, 0, stream>>>(src, dst, cursor2d, ebuf, e, nbkt, chunk);
    k_bsort<<<nbkt, 256, 0, stream>>>(ebuf, bbase, csr, rp, re, invd, perm, n);

    // layer 1
    k_agg<0><<<AGG_GRID, 256, 0, stream>>>((const uint4*)hf0, rp, re, csr, invd, perm,
                                           nullptr, nullptr, (uint4*)tb, n);
    k_mm<1, 1><<<MM_GRID, 256, 0, stream>>>(tb, Wt1, b1, yb, nullptr, acc1, n);
    k_bnfin<<<1, FD, 0, stream>>>(acc1, g1, be1, na1, nc1, invN);

    // layer 2
    k_agg<1><<<AGG_GRID, 256, 0, stream>>>((const uint4*)yb, rp, re, csr, invd, perm,
                                           na1, nc1, (uint4*)tb, n);
    k_mm<1, 1><<<MM_GRID, 256, 0, stream>>>(tb, Wt2, b2, yb, nullptr, acc2, n);
    k_bnfin<<<1, FD, 0, stream>>>(acc2, g2, be2, na2, nc2, invN);

    // layer 3
    k_agg<1><<<AGG_GRID, 256, 0, stream>>>((const uint4*)yb, rp, re, csr, invd, perm,
                                           na2, nc2, (uint4*)tb, n);
    k_mm<0, 0><<<MM_GRID, 256, 0, stream>>>(tb, Wt3, b3, nullptr, O, nullptr, n);
}